// Round 16
// baseline (189.244 us; speedup 1.0000x reference)
//
#include <hip/hip_runtime.h>
#include <stdint.h>

#define SLEN 2048
#define EDIM 1024
#define NH 16
#define HD 64
#define QLD 1152   // qkv packed row: [q 0..1023 | k 1024..1087 | v 1088..1151]
#define NSPLIT 2   // attn split-K over key halves (R3-verified config)

typedef unsigned short u16;
typedef short bf8 __attribute__((ext_vector_type(8)));   // 8 bf16 in 4 VGPRs
typedef float f4 __attribute__((ext_vector_type(4)));
typedef float f16f __attribute__((ext_vector_type(16)));
typedef int v2i __attribute__((ext_vector_type(2)));
typedef bf8 bf8_a __attribute__((may_alias));
typedef uint2 uint2_a __attribute__((may_alias));
typedef uint4 uint4_a __attribute__((may_alias));

__device__ __forceinline__ float bf2f(u16 u) {
  union { unsigned u; float f; } c; c.u = ((unsigned)u) << 16; return c.f;
}
__device__ __forceinline__ u16 f2bf(float x) {
  union { __bf16 h; u16 u; } c; c.h = (__bf16)x; return c.u;  // HW cvt, RNE
}
__device__ __forceinline__ unsigned pk2bf(float a, float b) {
  union { __bf16 h[2]; unsigned u; } c;
  c.h[0] = (__bf16)a; c.h[1] = (__bf16)b;
  return c.u;
}
__device__ __forceinline__ void async_cp16(u16* lds, const u16* g) {
  __builtin_amdgcn_global_load_lds((__attribute__((address_space(1))) void*)g,
                                   (__attribute__((address_space(3))) void*)lds,
                                   16, 0, 0);
}

// ---------------- fused prep: weight transposes + bias + x-convert -----------
__device__ __forceinline__ void tcvt_tile(const float* src, int srcLd,
                                          u16* dst, int dstLd, int r0, int c0) {
  __shared__ u16 tile[64][65];
  const int t = threadIdx.x;
#pragma unroll
  for (int i = 0; i < 16; ++i) {
    int e = i * 256 + t, rr = e >> 6, cc = e & 63;
    tile[rr][cc] = f2bf(src[(size_t)(r0 + rr) * srcLd + c0 + cc]);
  }
  __syncthreads();
#pragma unroll
  for (int i = 0; i < 16; ++i) {
    int e = i * 256 + t, j = e >> 6, ii = e & 63;
    dst[(size_t)(c0 + j) * dstLd + r0 + ii] = tile[ii][j];
  }
}

__global__ void prep_w(const float* wq, const float* wk, const float* wv,
                       const float* wo, const float* bq, const float* bk,
                       const float* bv, const float* bo, const float* x,
                       u16* wT, u16* woT, float* bQKV, float* bOut, u16* xbf) {
  const int yy = blockIdx.y;
  if (yy < 16) tcvt_tile(wq, 1024, wT, 1024, blockIdx.x * 64, yy * 64);
  else if (yy < 32) tcvt_tile(wo, 1024, woT, 1024, blockIdx.x * 64, (yy - 16) * 64);
  else if (yy == 32) tcvt_tile(wk, 64, wT + (size_t)1024 * 1024, 1024, blockIdx.x * 64, 0);
  else if (yy == 33) tcvt_tile(wv, 64, wT + (size_t)1088 * 1024, 1024, blockIdx.x * 64, 0);
  else if (yy == 34) {
    int i = blockIdx.x * 256 + threadIdx.x;
    if (i < 1024) bQKV[i] = bq[i];
    else if (i < 1088) bQKV[i] = bk[i - 1024];
    else if (i < 1152) bQKV[i] = bv[i - 1088];
    int j = i - 1152;
    if (j >= 0 && j < 1024) bOut[j] = bo[j];
  } else {
    // x fp32 -> bf16: 256 blocks x 256 thr x 64 elems = 4M
    const int blk = (yy - 35) * 16 + blockIdx.x, t = threadIdx.x;
#pragma unroll
    for (int i = 0; i < 8; ++i) {
      int idx = blk * 16384 + i * 2048 + t * 8;
      u16 tmp[8];
#pragma unroll
      for (int j = 0; j < 8; ++j) tmp[j] = f2bf(x[idx + j]);
      *(uint4_a*)&xbf[idx] = *(const uint4_a*)tmp;
    }
  }
}

// ---------------- 64x128 bf16 GEMM, B^T input, async staging -----------------
// R24 (verified): R3 64x128 single-buffer form + q-column pre-scale by
// C1 = 0.125*log2(e) when producing QKV (folds softmax scale out of attn).
// R28: when OpA != nullptr (out-proj), A staged by register-combining the
// split-K partials ((O0+O1)/(l0+l1)) — reduce_o + aob round-trip deleted.
// R29: R28 regressed because the reg-loads were issued synchronously between
// the barriers (16 x ~500cyc exposed). Fix: software-pipeline — prefetch
// iter it+1's Opart/lpart registers right after iter it's ds_write; they
// land during the compute phase. Only combine+ds_write remain on the
// critical path.
__global__ __launch_bounds__(256) void gemm_bt_bias(
    const u16* __restrict__ A, const u16* __restrict__ Bt,
    const float* __restrict__ bias, void* __restrict__ C, int K, int ldc,
    int ofp32, u16* __restrict__ vtb,
    const u16* __restrict__ OpA, const float* __restrict__ lpA) {
  __shared__ __align__(16) u16 As[64 * 64];
  __shared__ __align__(16) u16 Bs[128 * 64];
  const int tn0 = blockIdx.x * 128, tm0 = blockIdx.y * 64;
  const int tid = threadIdx.x, wave = tid >> 6, lane = tid & 63;
  const int quad = lane >> 4, l16 = lane & 15;
  const int wm = wave & 1, wn = wave >> 1;

  f4 acc[2][4];
#pragma unroll
  for (int i = 0; i < 2; ++i)
#pragma unroll
    for (int j = 0; j < 4; ++j) acc[i][j] = f4{0.f, 0.f, 0.f, 0.f};

  int aslot[2], bslot[4]; size_t aoff[2], boff[4];
  int am[2], ac[2];
#pragma unroll
  for (int i = 0; i < 2; ++i) {
    int s = i * 256 + tid, m = s >> 3, kc = s & 7, c = (kc - m) & 7;
    aslot[i] = s; aoff[i] = (size_t)(tm0 + m) * K + c * 8;
    am[i] = m; ac[i] = c;
  }
#pragma unroll
  for (int i = 0; i < 4; ++i) {
    int s = i * 256 + tid, n = s >> 3, kc = s & 7, c = (kc - n) & 7;
    bslot[i] = s; boff[i] = (size_t)(tn0 + n) * K + c * 8;
  }
  int ard[2][2], brd[4][2];
#pragma unroll
  for (int mi = 0; mi < 2; ++mi) {
    int m = wm * 32 + mi * 16 + l16;
#pragma unroll
    for (int kk = 0; kk < 2; ++kk)
      ard[mi][kk] = (m * 8 + (((kk * 4 + quad) + m) & 7)) * 8;
  }
#pragma unroll
  for (int ni = 0; ni < 4; ++ni) {
    int n = wn * 64 + ni * 16 + l16;
#pragma unroll
    for (int kk = 0; kk < 2; ++kk)
      brd[ni][kk] = (n * 8 + (((kk * 4 + quad) + n) & 7)) * 8;
  }

  // fused-A precompute: per-chunk Opart base indices (row part; head added/iter)
  size_t apbase[2]; int ablk[2];
#pragma unroll
  for (int i = 0; i < 2; ++i) {
    int grow = tm0 + am[i];            // global q-row 0..4095
    int b = grow >> 11, g = grow & 2047;
    ablk[i] = (b << 4);                // bh base = b*16 (+head per iter)
    apbase[i] = (size_t)(g >> 8) * 256 + (g & 255);  // blk*256 + loc
  }

  // prefetch registers for fused A-staging (one K-iter ahead)
  uint4 pf0[2], pf1[2]; float pfl[2];
  auto prefetchA = [&](int it) {
#pragma unroll
    for (int i = 0; i < 2; ++i) {
      int bh = ablk[i] + it;
      size_t p0 = (size_t)(bh * 8) * 256 + apbase[i];
      size_t p1 = (size_t)((32 + bh) * 8) * 256 + apbase[i];
      pf0[i] = *(const uint4_a*)(OpA + p0 * 64 + ac[i] * 8);
      pf1[i] = *(const uint4_a*)(OpA + p1 * 64 + ac[i] * 8);
      pfl[i] = lpA[p0] + lpA[p1];
    }
  };
  if (OpA != nullptr) prefetchA(0);

  const int kIt = K >> 6;
  for (int it = 0; it < kIt; ++it) {
    __syncthreads();
    const size_t kb = (size_t)it * 64;
    if (OpA == nullptr) {
#pragma unroll
      for (int i = 0; i < 2; ++i) async_cp16(&As[aslot[i] * 8], A + aoff[i] + kb);
    } else {
      // consume prefetched regs (loaded a full compute phase ago)
#pragma unroll
      for (int i = 0; i < 2; ++i) {
        float inv = 1.f / pfl[i];
        const u16* q0 = (const u16*)&pf0[i];
        const u16* q1 = (const u16*)&pf1[i];
        u16 outv[8];
#pragma unroll
        for (int j = 0; j < 8; ++j)
          outv[j] = f2bf((bf2f(q0[j]) + bf2f(q1[j])) * inv);
        *(uint4_a*)&As[aslot[i] * 8] = *(const uint4_a*)outv;
      }
      if (it + 1 < kIt) prefetchA(it + 1);  // lands during compute phase
    }
#pragma unroll
    for (int i = 0; i < 4; ++i) async_cp16(&Bs[bslot[i] * 8], Bt + boff[i] + kb);
    __syncthreads();
#pragma unroll
    for (int kk = 0; kk < 2; ++kk) {
      bf8 af[2], bfr[4];
#pragma unroll
      for (int mi = 0; mi < 2; ++mi) af[mi] = *(const bf8_a*)&As[ard[mi][kk]];
#pragma unroll
      for (int ni = 0; ni < 4; ++ni) bfr[ni] = *(const bf8_a*)&Bs[brd[ni][kk]];
#pragma unroll
      for (int mi = 0; mi < 2; ++mi)
#pragma unroll
        for (int ni = 0; ni < 4; ++ni)
          acc[mi][ni] = __builtin_amdgcn_mfma_f32_16x16x32_bf16(
              af[mi], bfr[ni], acc[mi][ni], 0, 0, 0);
    }
  }

  const float QSCALE = 0.125f * 1.44269504089f;  // softmax scale * log2(e)
  float bv[4];
#pragma unroll
  for (int ni = 0; ni < 4; ++ni) bv[ni] = bias[tn0 + wn * 64 + ni * 16 + l16];
#pragma unroll
  for (int mi = 0; mi < 2; ++mi) {
    int row0 = tm0 + wm * 32 + mi * 16 + quad * 4;
#pragma unroll
    for (int ni = 0; ni < 4; ++ni) {
      int col = tn0 + wn * 64 + ni * 16 + l16;
      float vv[4];
#pragma unroll
      for (int r = 0; r < 4; ++r) vv[r] = acc[mi][ni][r] + bv[ni];
      if (vtb != nullptr && col < 1024) {
#pragma unroll
        for (int r = 0; r < 4; ++r) vv[r] *= QSCALE;  // pre-scale q for attn
      }
      if (ofp32) {
#pragma unroll
        for (int r = 0; r < 4; ++r)
          ((float*)C)[(size_t)(row0 + r) * ldc + col] = vv[r];
      } else {
#pragma unroll
        for (int r = 0; r < 4; ++r)
          ((u16*)C)[(size_t)(row0 + r) * ldc + col] = f2bf(vv[r]);
      }
      if (vtb != nullptr && col >= 1088) {
        int d = col - 1088, bb = row0 >> 11, s0 = row0 & 2047;
        uint2 pk;
        pk.x = pk2bf(vv[0], vv[1]);
        pk.y = pk2bf(vv[2], vv[3]);
        *(uint2_a*)&vtb[(size_t)(bb * 64 + d) * SLEN + s0] = pk;
      }
    }
  }
}

// ---------------- flash attention (MQA), split-K=2, QBLK=256, KVBLK=128 ------
// R18/R24/R26/R27 (verified): 32x32x16 MFMA, permlane in-register softmax, q
// pre-scaled in GEMM, 2 q-sets/wave sharing K/V frags, 8 epochs of 128 keys.
// attn measured flat ~55-59us across all structural variants; kept as-is.
__global__ __launch_bounds__(256, 2) void attn_kernel(
    const u16* __restrict__ qkv, const u16* __restrict__ vT,
    u16* __restrict__ Opart, float* __restrict__ lpart) {
  __shared__ __align__(16) u16 Kf[2][8192];  // [buf][128 keys x 64 d] frag-major
  __shared__ __align__(16) u16 Vf[2][8192];  // [buf][64 d x 128 keys] frag-major
  const int qt = blockIdx.x, bh = blockIdx.y, ks = blockIdx.z;
  const int b = bh >> 4, h = bh & 15;
  const int tid = threadIdx.x, wave = tid >> 6, lane = tid & 63;
  const int l31 = lane & 31, hi = lane >> 5, r16l = lane & 15;
  // shared lane-base for all frag-major LDS addressing: [g16][hi][r16]
  const int base_k = (l31 >> 4) * 64 + hi * 16 + r16l;

  // Q prologue: 256 rows (qt*256..+255) into Kf[0..1] (16384 u16 = 256x64)
  u16* Kflat = &Kf[0][0];
#pragma unroll
  for (int i = 0; i < 8; ++i) {
    int d = i * 256 + tid;           // 0..2047
    int sel = d >> 10, dl = d & 1023;
    int kk = dl >> 9, g = (dl >> 6) & 7, qd = (dl >> 4) & 3, r16 = dl & 15;
    async_cp16(&Kflat[(sel * 1024 + dl) * 8],
               qkv + (size_t)(b * SLEN + qt * 256 + sel * 128 + g * 16 + r16) * QLD +
                   h * HD + (kk * 4 + qd) * 8);
  }
  __syncthreads();
  // Q B-frags: wave w owns q rows w*64..+63; qset s covers +s*32..+32.
  // 1024-chunk half = w>>1; within-half q-group gq = (w&1)*2 + s.
  bf8 bq[2][4];
  {
    const u16* srcf = Kflat + (wave >> 1) * 8192;
#pragma unroll
    for (int qset = 0; qset < 2; ++qset) {
      int gq = (wave & 1) * 2 + qset;
#pragma unroll
      for (int kk2 = 0; kk2 < 4; ++kk2) {
        int c = base_k + gq * 128 + (kk2 >> 1) * 512 + (kk2 & 1) * 32;
        bq[qset][kk2] = *(const bf8_a*)&srcf[c * 8];
      }
    }
  }
  __syncthreads();  // bq reads complete before Kf reused for K tiles

  const int kbase = ks * (SLEN / NSPLIT);  // 1024-key range per split
  // persistent staging pointers (strength-reduced addressing)
  const u16* kp[2]; const u16* vp[2];
#pragma unroll
  for (int i = 0; i < 2; ++i) {
    int d = i * 256 + tid;
    int kk = d >> 8, k8 = (d >> 6) & 3, qd = (d >> 4) & 3, r16 = d & 15;
    kp[i] = qkv + (size_t)(b * SLEN + kbase + k8 * 16 + r16) * QLD + EDIM +
            (kk * 4 + qd) * 8;
    int k4 = d >> 8, ni = (d >> 6) & 3;
    vp[i] = vT + (size_t)(b * 64 + ni * 16 + r16) * SLEN + kbase +
            (k4 * 4 + qd) * 8;
  }
  // stage 128 keys (two 64-key subtiles) into buffer bsel
  auto stage = [&](int bsel) {
#pragma unroll
    for (int s = 0; s < 2; ++s)
#pragma unroll
      for (int i = 0; i < 2; ++i) {
        int d = i * 256 + tid;
        async_cp16(&Kf[bsel][s * 4096 + d * 8], kp[i] + s * 64 * QLD);
        async_cp16(&Vf[bsel][s * 4096 + d * 8], vp[i] + s * 64);
      }
#pragma unroll
    for (int i = 0; i < 2; ++i) { kp[i] += 128 * QLD; vp[i] += 128; }
  };
  stage(0);

  f16f acc_o[2][2];  // [qset][ni2]
#pragma unroll
  for (int qset = 0; qset < 2; ++qset)
#pragma unroll
    for (int i = 0; i < 2; ++i)
#pragma unroll
      for (int r = 0; r < 16; ++r) acc_o[qset][i][r] = 0.f;
  f4 lracc[2] = {f4{0.f, 0.f, 0.f, 0.f}, f4{0.f, 0.f, 0.f, 0.f}};

  const int NHALF = SLEN / NSPLIT / 128;  // 8 epochs of 128 keys
  for (int hh = 0; hh < NHALF; ++hh) {
    __syncthreads();  // drains staging of epoch hh; fences buffer reuse
    if (hh < NHALF - 1) stage((hh + 1) & 1);
    const int bsel = hh & 1;

#pragma unroll
    for (int sub = 0; sub < 2; ++sub) {
      const u16* kf = &Kf[bsel][sub * 4096];
      const u16* vf = &Vf[bsel][sub * 4096];

      // two 32-key groups per subtile; each K/V frag feeds BOTH q-sets
#pragma unroll
      for (int j32 = 0; j32 < 2; ++j32) {
        f16f st0, st1;
#pragma unroll
        for (int r = 0; r < 16; ++r) { st0[r] = 0.f; st1[r] = 0.f; }
        __builtin_amdgcn_s_setprio(1);
#pragma unroll
        for (int kk2 = 0; kk2 < 4; ++kk2) {
          bf8 ak = *(const bf8_a*)
              &kf[(base_k + (kk2 >> 1) * 256 + j32 * 128 + (kk2 & 1) * 32) * 8];
          st0 = __builtin_amdgcn_mfma_f32_32x32x16_bf16(ak, bq[0][kk2], st0, 0, 0, 0);
          st1 = __builtin_amdgcn_mfma_f32_32x32x16_bf16(ak, bq[1][kk2], st1, 0, 0, 0);
        }
        __builtin_amdgcn_s_setprio(0);

        // softmax numerator + in-register transpose, both q-sets
        bf8 pa[2][2];
#pragma unroll
        for (int qset = 0; qset < 2; ++qset) {
          float pe[16];
#pragma unroll
          for (int r = 0; r < 16; ++r) {
            pe[r] = __builtin_amdgcn_exp2f(qset ? st1[r] : st0[r]);
            lracc[qset][r & 3] += pe[r];
          }
          int a0 = (int)pk2bf(pe[0], pe[1]),   b0 = (int)pk2bf(pe[4], pe[5]);
          int a1 = (int)pk2bf(pe[2], pe[3]),   b1 = (int)pk2bf(pe[6], pe[7]);
          int a2 = (int)pk2bf(pe[8], pe[9]),   b2 = (int)pk2bf(pe[12], pe[13]);
          int a3 = (int)pk2bf(pe[10], pe[11]), b3 = (int)pk2bf(pe[14], pe[15]);
          v2i s0 = __builtin_amdgcn_permlane32_swap(a0, b0, false, false);
          v2i s1 = __builtin_amdgcn_permlane32_swap(a1, b1, false, false);
          v2i s2 = __builtin_amdgcn_permlane32_swap(a2, b2, false, false);
          v2i s3 = __builtin_amdgcn_permlane32_swap(a3, b3, false, false);
          union { int i[4]; bf8 v; } up0, up1;
          up0.i[0] = s0[0]; up0.i[1] = s1[0]; up0.i[2] = s0[1]; up0.i[3] = s1[1];
          up1.i[0] = s2[0]; up1.i[1] = s3[0]; up1.i[2] = s2[1]; up1.i[3] = s3[1];
          pa[qset][0] = up0.v;
          pa[qset][1] = up1.v;
        }

        __builtin_amdgcn_s_setprio(1);
#pragma unroll
        for (int ks2 = 0; ks2 < 2; ++ks2)
#pragma unroll
          for (int ni2 = 0; ni2 < 2; ++ni2) {
            bf8 bv = *(const bf8_a*)
                &vf[(base_k + j32 * 256 + ni2 * 128 + ks2 * 32) * 8];
            acc_o[0][ni2] = __builtin_amdgcn_mfma_f32_32x32x16_bf16(
                pa[0][ks2], bv, acc_o[0][ni2], 0, 0, 0);
            acc_o[1][ni2] = __builtin_amdgcn_mfma_f32_32x32x16_bf16(
                pa[1][ks2], bv, acc_o[1][ni2], 0, 0, 0);
          }
        __builtin_amdgcn_s_setprio(0);
      }
    }
  }

  // store unnormalized partials: O bf16, l fp32 (256 q-rows per block)
  const size_t pbase = (size_t)((ks * 32 + bh) * 8 + qt) * 256;
#pragma unroll
  for (int qset = 0; qset < 2; ++qset) {
    float lr = (lracc[qset][0] + lracc[qset][1]) + (lracc[qset][2] + lracc[qset][3]);
    float s = lr + __shfl_xor(lr, 32, 64);
    if (lane < 32) lpart[pbase + wave * 64 + qset * 32 + lane] = s;
  }
#pragma unroll
  for (int qset = 0; qset < 2; ++qset)
#pragma unroll
    for (int ni2 = 0; ni2 < 2; ++ni2)
#pragma unroll
      for (int r = 0; r < 16; ++r) {
        int q = (r & 3) + 8 * (r >> 2) + 4 * hi;
        Opart[(pbase + wave * 64 + qset * 32 + q) * 64 + ni2 * 32 + l31] =
            f2bf(acc_o[qset][ni2][r]);
      }
}

// ---------------- host ------------------------------------------------------
extern "C" void kernel_launch(void* const* d_in, const int* in_sizes, int n_in,
                              void* d_out, int out_size, void* d_ws, size_t ws_size,
                              hipStream_t stream) {
  const float* x  = (const float*)d_in[0];
  const float* wq = (const float*)d_in[1];
  const float* bq = (const float*)d_in[2];
  const float* wk = (const float*)d_in[3];
  const float* bk = (const float*)d_in[4];
  const float* wv = (const float*)d_in[5];
  const float* bv = (const float*)d_in[6];
  const float* wo = (const float*)d_in[7];
  const float* bo = (const float*)d_in[8];

  char* ws = (char*)d_ws;
  size_t off = 0;
  auto carve = [&](size_t bytes) {
    void* p = ws + off;
    off = (off + bytes + 255) & ~(size_t)255;
    return p;
  };
  u16* wT      = (u16*)carve((size_t)1152 * 1024 * 2);  // packed [wq|wk|wv]^T
  u16* woT     = (u16*)carve((size_t)1024 * 1024 * 2);
  float* bQKV  = (float*)carve(1152 * 4);
  float* bOut  = (float*)carve(1024 * 4);
  u16* xbf     = (u16*)carve((size_t)4096 * EDIM * 2);
  u16* qkvb    = (u16*)carve((size_t)4096 * QLD * 2);
  u16* vTb     = (u16*)carve((size_t)2 * 64 * SLEN * 2);
  u16* Opart   = (u16*)carve((size_t)NSPLIT * 32 * 8 * 256 * 64 * 2);  // 16.8 MB
  float* lpart = (float*)carve((size_t)NSPLIT * 32 * 8 * 256 * 4);     // 0.5 MB

  // prep: weight transposes + bias + x-convert (one grid)
  prep_w<<<dim3(16, 51), 256, 0, stream>>>(wq, wk, wv, wo, bq, bk, bv, bo, x,
                                           wT, woT, bQKV, bOut, xbf);

  // QKV projection (+ fused V-transpose): [4096][1024] @ [1024][1152]^T
  gemm_bt_bias<<<dim3(9, 64), 256, 0, stream>>>(xbf, wT, bQKV, qkvb, 1024, QLD,
                                                0, vTb, nullptr, nullptr);

  // flash attention, split-K over key halves (QBLK=256, KVBLK=128)
  attn_kernel<<<dim3(8, 32, NSPLIT), 256, 0, stream>>>(qkvb, vTb, Opart, lpart);

  // output projection + bo -> d_out (fp32); A staged by pipelined fused combine
  gemm_bt_bias<<<dim3(8, 64), 256, 0, stream>>>(nullptr, woT, bOut, d_out, 1024,
                                                1024, 1, nullptr, Opart, lpart);
}

// Round 19
// 177.895 us; speedup vs baseline: 1.0638x; 1.0638x over previous
//
#include <hip/hip_runtime.h>
#include <stdint.h>

#define SLEN 2048
#define EDIM 1024
#define NH 16
#define HD 64
#define QLD 1152   // qkv packed row: [q 0..1023 | k 1024..1087 | v 1088..1151]
#define NSPLIT 2   // attn split-K over key halves (R3-verified config)

typedef unsigned short u16;
typedef short bf8 __attribute__((ext_vector_type(8)));   // 8 bf16 in 4 VGPRs
typedef float f4 __attribute__((ext_vector_type(4)));
typedef float f16f __attribute__((ext_vector_type(16)));
typedef int v2i __attribute__((ext_vector_type(2)));
typedef bf8 bf8_a __attribute__((may_alias));
typedef uint2 uint2_a __attribute__((may_alias));
typedef uint4 uint4_a __attribute__((may_alias));

__device__ __forceinline__ float bf2f(u16 u) {
  union { unsigned u; float f; } c; c.u = ((unsigned)u) << 16; return c.f;
}
__device__ __forceinline__ u16 f2bf(float x) {
  union { __bf16 h; u16 u; } c; c.h = (__bf16)x; return c.u;  // HW cvt, RNE
}
__device__ __forceinline__ unsigned pk2bf(float a, float b) {
  union { __bf16 h[2]; unsigned u; } c;
  c.h[0] = (__bf16)a; c.h[1] = (__bf16)b;
  return c.u;
}
__device__ __forceinline__ void async_cp16(u16* lds, const u16* g) {
  __builtin_amdgcn_global_load_lds((__attribute__((address_space(1))) void*)g,
                                   (__attribute__((address_space(3))) void*)lds,
                                   16, 0, 0);
}

// ---------------- fused prep: weight transposes + bias + x-convert -----------
__device__ __forceinline__ void tcvt_tile(const float* src, int srcLd,
                                          u16* dst, int dstLd, int r0, int c0) {
  __shared__ u16 tile[64][65];
  const int t = threadIdx.x;
#pragma unroll
  for (int i = 0; i < 16; ++i) {
    int e = i * 256 + t, rr = e >> 6, cc = e & 63;
    tile[rr][cc] = f2bf(src[(size_t)(r0 + rr) * srcLd + c0 + cc]);
  }
  __syncthreads();
#pragma unroll
  for (int i = 0; i < 16; ++i) {
    int e = i * 256 + t, j = e >> 6, ii = e & 63;
    dst[(size_t)(c0 + j) * dstLd + r0 + ii] = tile[ii][j];
  }
}

__global__ void prep_w(const float* wq, const float* wk, const float* wv,
                       const float* wo, const float* bq, const float* bk,
                       const float* bv, const float* bo, const float* x,
                       u16* wT, u16* woT, float* bQKV, float* bOut, u16* xbf) {
  const int yy = blockIdx.y;
  if (yy < 16) tcvt_tile(wq, 1024, wT, 1024, blockIdx.x * 64, yy * 64);
  else if (yy < 32) tcvt_tile(wo, 1024, woT, 1024, blockIdx.x * 64, (yy - 16) * 64);
  else if (yy == 32) tcvt_tile(wk, 64, wT + (size_t)1024 * 1024, 1024, blockIdx.x * 64, 0);
  else if (yy == 33) tcvt_tile(wv, 64, wT + (size_t)1088 * 1024, 1024, blockIdx.x * 64, 0);
  else if (yy == 34) {
    int i = blockIdx.x * 256 + threadIdx.x;
    if (i < 1024) bQKV[i] = bq[i];
    else if (i < 1088) bQKV[i] = bk[i - 1024];
    else if (i < 1152) bQKV[i] = bv[i - 1088];
    int j = i - 1152;
    if (j >= 0 && j < 1024) bOut[j] = bo[j];
  } else {
    // x fp32 -> bf16: 256 blocks x 256 thr x 64 elems = 4M
    const int blk = (yy - 35) * 16 + blockIdx.x, t = threadIdx.x;
#pragma unroll
    for (int i = 0; i < 8; ++i) {
      int idx = blk * 16384 + i * 2048 + t * 8;
      u16 tmp[8];
#pragma unroll
      for (int j = 0; j < 8; ++j) tmp[j] = f2bf(x[idx + j]);
      *(uint4_a*)&xbf[idx] = *(const uint4_a*)tmp;
    }
  }
}

// ---------------- 64x128 bf16 GEMM, B^T input, async staging -----------------
// R24 (verified): R3 64x128 single-buffer form + q-column pre-scale by
// C1 = 0.125*log2(e) when producing QKV (folds softmax scale out of attn).
// R30: fused split-K combine (R28/R29) reverted — both variants regressed
// (sync loads on critical path / VGPR inflation of the shared kernel).
__global__ __launch_bounds__(256) void gemm_bt_bias(
    const u16* __restrict__ A, const u16* __restrict__ Bt,
    const float* __restrict__ bias, void* __restrict__ C, int K, int ldc,
    int ofp32, u16* __restrict__ vtb) {
  __shared__ __align__(16) u16 As[64 * 64];
  __shared__ __align__(16) u16 Bs[128 * 64];
  const int tn0 = blockIdx.x * 128, tm0 = blockIdx.y * 64;
  const int tid = threadIdx.x, wave = tid >> 6, lane = tid & 63;
  const int quad = lane >> 4, l16 = lane & 15;
  const int wm = wave & 1, wn = wave >> 1;

  f4 acc[2][4];
#pragma unroll
  for (int i = 0; i < 2; ++i)
#pragma unroll
    for (int j = 0; j < 4; ++j) acc[i][j] = f4{0.f, 0.f, 0.f, 0.f};

  int aslot[2], bslot[4]; size_t aoff[2], boff[4];
#pragma unroll
  for (int i = 0; i < 2; ++i) {
    int s = i * 256 + tid, m = s >> 3, kc = s & 7, c = (kc - m) & 7;
    aslot[i] = s; aoff[i] = (size_t)(tm0 + m) * K + c * 8;
  }
#pragma unroll
  for (int i = 0; i < 4; ++i) {
    int s = i * 256 + tid, n = s >> 3, kc = s & 7, c = (kc - n) & 7;
    bslot[i] = s; boff[i] = (size_t)(tn0 + n) * K + c * 8;
  }
  int ard[2][2], brd[4][2];
#pragma unroll
  for (int mi = 0; mi < 2; ++mi) {
    int m = wm * 32 + mi * 16 + l16;
#pragma unroll
    for (int kk = 0; kk < 2; ++kk)
      ard[mi][kk] = (m * 8 + (((kk * 4 + quad) + m) & 7)) * 8;
  }
#pragma unroll
  for (int ni = 0; ni < 4; ++ni) {
    int n = wn * 64 + ni * 16 + l16;
#pragma unroll
    for (int kk = 0; kk < 2; ++kk)
      brd[ni][kk] = (n * 8 + (((kk * 4 + quad) + n) & 7)) * 8;
  }

  const int kIt = K >> 6;
  for (int it = 0; it < kIt; ++it) {
    __syncthreads();
    const size_t kb = (size_t)it * 64;
#pragma unroll
    for (int i = 0; i < 2; ++i) async_cp16(&As[aslot[i] * 8], A + aoff[i] + kb);
#pragma unroll
    for (int i = 0; i < 4; ++i) async_cp16(&Bs[bslot[i] * 8], Bt + boff[i] + kb);
    __syncthreads();
#pragma unroll
    for (int kk = 0; kk < 2; ++kk) {
      bf8 af[2], bfr[4];
#pragma unroll
      for (int mi = 0; mi < 2; ++mi) af[mi] = *(const bf8_a*)&As[ard[mi][kk]];
#pragma unroll
      for (int ni = 0; ni < 4; ++ni) bfr[ni] = *(const bf8_a*)&Bs[brd[ni][kk]];
#pragma unroll
      for (int mi = 0; mi < 2; ++mi)
#pragma unroll
        for (int ni = 0; ni < 4; ++ni)
          acc[mi][ni] = __builtin_amdgcn_mfma_f32_16x16x32_bf16(
              af[mi], bfr[ni], acc[mi][ni], 0, 0, 0);
    }
  }

  const float QSCALE = 0.125f * 1.44269504089f;  // softmax scale * log2(e)
  float bv[4];
#pragma unroll
  for (int ni = 0; ni < 4; ++ni) bv[ni] = bias[tn0 + wn * 64 + ni * 16 + l16];
#pragma unroll
  for (int mi = 0; mi < 2; ++mi) {
    int row0 = tm0 + wm * 32 + mi * 16 + quad * 4;
#pragma unroll
    for (int ni = 0; ni < 4; ++ni) {
      int col = tn0 + wn * 64 + ni * 16 + l16;
      float vv[4];
#pragma unroll
      for (int r = 0; r < 4; ++r) vv[r] = acc[mi][ni][r] + bv[ni];
      if (vtb != nullptr && col < 1024) {
#pragma unroll
        for (int r = 0; r < 4; ++r) vv[r] *= QSCALE;  // pre-scale q for attn
      }
      if (ofp32) {
#pragma unroll
        for (int r = 0; r < 4; ++r)
          ((float*)C)[(size_t)(row0 + r) * ldc + col] = vv[r];
      } else {
#pragma unroll
        for (int r = 0; r < 4; ++r)
          ((u16*)C)[(size_t)(row0 + r) * ldc + col] = f2bf(vv[r]);
      }
      if (vtb != nullptr && col >= 1088) {
        int d = col - 1088, bb = row0 >> 11, s0 = row0 & 2047;
        uint2 pk;
        pk.x = pk2bf(vv[0], vv[1]);
        pk.y = pk2bf(vv[2], vv[3]);
        *(uint2_a*)&vtb[(size_t)(bb * 64 + d) * SLEN + s0] = pk;
      }
    }
  }
}

// ---------------- flash attention (MQA), split-K=2, QBLK=256, KVBLK=128 ------
// R18/R24/R26/R27 (verified): 32x32x16 MFMA, permlane in-register softmax, q
// pre-scaled in GEMM, 2 q-sets/wave sharing K/V frags, 8 epochs of 128 keys.
// attn measured ~55-56.5us stable across R27/R28/R29; this is the best config.
__global__ __launch_bounds__(256, 2) void attn_kernel(
    const u16* __restrict__ qkv, const u16* __restrict__ vT,
    u16* __restrict__ Opart, float* __restrict__ lpart) {
  __shared__ __align__(16) u16 Kf[2][8192];  // [buf][128 keys x 64 d] frag-major
  __shared__ __align__(16) u16 Vf[2][8192];  // [buf][64 d x 128 keys] frag-major
  const int qt = blockIdx.x, bh = blockIdx.y, ks = blockIdx.z;
  const int b = bh >> 4, h = bh & 15;
  const int tid = threadIdx.x, wave = tid >> 6, lane = tid & 63;
  const int l31 = lane & 31, hi = lane >> 5, r16l = lane & 15;
  // shared lane-base for all frag-major LDS addressing: [g16][hi][r16]
  const int base_k = (l31 >> 4) * 64 + hi * 16 + r16l;

  // Q prologue: 256 rows (qt*256..+255) into Kf[0..1] (16384 u16 = 256x64)
  u16* Kflat = &Kf[0][0];
#pragma unroll
  for (int i = 0; i < 8; ++i) {
    int d = i * 256 + tid;           // 0..2047
    int sel = d >> 10, dl = d & 1023;
    int kk = dl >> 9, g = (dl >> 6) & 7, qd = (dl >> 4) & 3, r16 = dl & 15;
    async_cp16(&Kflat[(sel * 1024 + dl) * 8],
               qkv + (size_t)(b * SLEN + qt * 256 + sel * 128 + g * 16 + r16) * QLD +
                   h * HD + (kk * 4 + qd) * 8);
  }
  __syncthreads();
  // Q B-frags: wave w owns q rows w*64..+63; qset s covers +s*32..+32.
  // 1024-chunk half = w>>1; within-half q-group gq = (w&1)*2 + s.
  bf8 bq[2][4];
  {
    const u16* srcf = Kflat + (wave >> 1) * 8192;
#pragma unroll
    for (int qset = 0; qset < 2; ++qset) {
      int gq = (wave & 1) * 2 + qset;
#pragma unroll
      for (int kk2 = 0; kk2 < 4; ++kk2) {
        int c = base_k + gq * 128 + (kk2 >> 1) * 512 + (kk2 & 1) * 32;
        bq[qset][kk2] = *(const bf8_a*)&srcf[c * 8];
      }
    }
  }
  __syncthreads();  // bq reads complete before Kf reused for K tiles

  const int kbase = ks * (SLEN / NSPLIT);  // 1024-key range per split
  // persistent staging pointers (strength-reduced addressing)
  const u16* kp[2]; const u16* vp[2];
#pragma unroll
  for (int i = 0; i < 2; ++i) {
    int d = i * 256 + tid;
    int kk = d >> 8, k8 = (d >> 6) & 3, qd = (d >> 4) & 3, r16 = d & 15;
    kp[i] = qkv + (size_t)(b * SLEN + kbase + k8 * 16 + r16) * QLD + EDIM +
            (kk * 4 + qd) * 8;
    int k4 = d >> 8, ni = (d >> 6) & 3;
    vp[i] = vT + (size_t)(b * 64 + ni * 16 + r16) * SLEN + kbase +
            (k4 * 4 + qd) * 8;
  }
  // stage 128 keys (two 64-key subtiles) into buffer bsel
  auto stage = [&](int bsel) {
#pragma unroll
    for (int s = 0; s < 2; ++s)
#pragma unroll
      for (int i = 0; i < 2; ++i) {
        int d = i * 256 + tid;
        async_cp16(&Kf[bsel][s * 4096 + d * 8], kp[i] + s * 64 * QLD);
        async_cp16(&Vf[bsel][s * 4096 + d * 8], vp[i] + s * 64);
      }
#pragma unroll
    for (int i = 0; i < 2; ++i) { kp[i] += 128 * QLD; vp[i] += 128; }
  };
  stage(0);

  f16f acc_o[2][2];  // [qset][ni2]
#pragma unroll
  for (int qset = 0; qset < 2; ++qset)
#pragma unroll
    for (int i = 0; i < 2; ++i)
#pragma unroll
      for (int r = 0; r < 16; ++r) acc_o[qset][i][r] = 0.f;
  f4 lracc[2] = {f4{0.f, 0.f, 0.f, 0.f}, f4{0.f, 0.f, 0.f, 0.f}};

  const int NHALF = SLEN / NSPLIT / 128;  // 8 epochs of 128 keys
  for (int hh = 0; hh < NHALF; ++hh) {
    __syncthreads();  // drains staging of epoch hh; fences buffer reuse
    if (hh < NHALF - 1) stage((hh + 1) & 1);
    const int bsel = hh & 1;

#pragma unroll
    for (int sub = 0; sub < 2; ++sub) {
      const u16* kf = &Kf[bsel][sub * 4096];
      const u16* vf = &Vf[bsel][sub * 4096];

      // two 32-key groups per subtile; each K/V frag feeds BOTH q-sets
#pragma unroll
      for (int j32 = 0; j32 < 2; ++j32) {
        f16f st0, st1;
#pragma unroll
        for (int r = 0; r < 16; ++r) { st0[r] = 0.f; st1[r] = 0.f; }
        __builtin_amdgcn_s_setprio(1);
#pragma unroll
        for (int kk2 = 0; kk2 < 4; ++kk2) {
          bf8 ak = *(const bf8_a*)
              &kf[(base_k + (kk2 >> 1) * 256 + j32 * 128 + (kk2 & 1) * 32) * 8];
          st0 = __builtin_amdgcn_mfma_f32_32x32x16_bf16(ak, bq[0][kk2], st0, 0, 0, 0);
          st1 = __builtin_amdgcn_mfma_f32_32x32x16_bf16(ak, bq[1][kk2], st1, 0, 0, 0);
        }
        __builtin_amdgcn_s_setprio(0);

        // softmax numerator + in-register transpose, both q-sets
        bf8 pa[2][2];
#pragma unroll
        for (int qset = 0; qset < 2; ++qset) {
          float pe[16];
#pragma unroll
          for (int r = 0; r < 16; ++r) {
            pe[r] = __builtin_amdgcn_exp2f(qset ? st1[r] : st0[r]);
            lracc[qset][r & 3] += pe[r];
          }
          int a0 = (int)pk2bf(pe[0], pe[1]),   b0 = (int)pk2bf(pe[4], pe[5]);
          int a1 = (int)pk2bf(pe[2], pe[3]),   b1 = (int)pk2bf(pe[6], pe[7]);
          int a2 = (int)pk2bf(pe[8], pe[9]),   b2 = (int)pk2bf(pe[12], pe[13]);
          int a3 = (int)pk2bf(pe[10], pe[11]), b3 = (int)pk2bf(pe[14], pe[15]);
          v2i s0 = __builtin_amdgcn_permlane32_swap(a0, b0, false, false);
          v2i s1 = __builtin_amdgcn_permlane32_swap(a1, b1, false, false);
          v2i s2 = __builtin_amdgcn_permlane32_swap(a2, b2, false, false);
          v2i s3 = __builtin_amdgcn_permlane32_swap(a3, b3, false, false);
          union { int i[4]; bf8 v; } up0, up1;
          up0.i[0] = s0[0]; up0.i[1] = s1[0]; up0.i[2] = s0[1]; up0.i[3] = s1[1];
          up1.i[0] = s2[0]; up1.i[1] = s3[0]; up1.i[2] = s2[1]; up1.i[3] = s3[1];
          pa[qset][0] = up0.v;
          pa[qset][1] = up1.v;
        }

        __builtin_amdgcn_s_setprio(1);
#pragma unroll
        for (int ks2 = 0; ks2 < 2; ++ks2)
#pragma unroll
          for (int ni2 = 0; ni2 < 2; ++ni2) {
            bf8 bv = *(const bf8_a*)
                &vf[(base_k + j32 * 256 + ni2 * 128 + ks2 * 32) * 8];
            acc_o[0][ni2] = __builtin_amdgcn_mfma_f32_32x32x16_bf16(
                pa[0][ks2], bv, acc_o[0][ni2], 0, 0, 0);
            acc_o[1][ni2] = __builtin_amdgcn_mfma_f32_32x32x16_bf16(
                pa[1][ks2], bv, acc_o[1][ni2], 0, 0, 0);
          }
        __builtin_amdgcn_s_setprio(0);
      }
    }
  }

  // store unnormalized partials: O bf16, l fp32 (256 q-rows per block)
  const size_t pbase = (size_t)((ks * 32 + bh) * 8 + qt) * 256;
#pragma unroll
  for (int qset = 0; qset < 2; ++qset) {
    float lr = (lracc[qset][0] + lracc[qset][1]) + (lracc[qset][2] + lracc[qset][3]);
    float s = lr + __shfl_xor(lr, 32, 64);
    if (lane < 32) lpart[pbase + wave * 64 + qset * 32 + lane] = s;
  }
#pragma unroll
  for (int qset = 0; qset < 2; ++qset)
#pragma unroll
    for (int ni2 = 0; ni2 < 2; ++ni2)
#pragma unroll
      for (int r = 0; r < 16; ++r) {
        int q = (r & 3) + 8 * (r >> 2) + 4 * hi;
        Opart[(pbase + wave * 64 + qset * 32 + q) * 64 + ni2 * 32 + l31] =
            f2bf(acc_o[qset][ni2][r]);
      }
}

// ---------------- combine split-K halves: aob = (ΣO_i)/(Σl_i) ----------------
// Partials live in 256-row blocks (8 qt); remap global row g.
__global__ __launch_bounds__(256) void reduce_o(const u16* __restrict__ Op,
                                                const float* __restrict__ lp,
                                                u16* __restrict__ aob) {
  const int qt = blockIdx.x, bh = blockIdx.y, b = bh >> 4, h = bh & 15;
  const int t = threadIdx.x, r = t >> 1, dh = (t & 1) * 32;
  const int g = qt * 128 + r;            // global q-row in 0..2047
  const int blk = g >> 8, loc = g & 255; // 256-row attn block / offset
  size_t p[NSPLIT];
#pragma unroll
  for (int i = 0; i < NSPLIT; ++i)
    p[i] = (size_t)((i * 32 + bh) * 8 + blk) * 256 + loc;
  float lsum = 0.f;
#pragma unroll
  for (int i = 0; i < NSPLIT; ++i) lsum += lp[p[i]];
  const float inv = 1.f / lsum;
  u16* dst = aob + (size_t)(b * SLEN + g) * EDIM + h * HD + dh;
#pragma unroll
  for (int c = 0; c < 4; ++c) {
    float accv[8] = {0.f, 0.f, 0.f, 0.f, 0.f, 0.f, 0.f, 0.f};
#pragma unroll
    for (int i = 0; i < NSPLIT; ++i) {
      uint4 a = *(const uint4_a*)(Op + p[i] * 64 + dh + c * 8);
      const u16* pa = (const u16*)&a;
#pragma unroll
      for (int j = 0; j < 8; ++j) accv[j] += bf2f(pa[j]);
    }
    u16 outv[8];
#pragma unroll
    for (int j = 0; j < 8; ++j) outv[j] = f2bf(accv[j] * inv);
    *(uint4_a*)(dst + c * 8) = *(const uint4_a*)outv;
  }
}

// ---------------- host ------------------------------------------------------
extern "C" void kernel_launch(void* const* d_in, const int* in_sizes, int n_in,
                              void* d_out, int out_size, void* d_ws, size_t ws_size,
                              hipStream_t stream) {
  const float* x  = (const float*)d_in[0];
  const float* wq = (const float*)d_in[1];
  const float* bq = (const float*)d_in[2];
  const float* wk = (const float*)d_in[3];
  const float* bk = (const float*)d_in[4];
  const float* wv = (const float*)d_in[5];
  const float* bv = (const float*)d_in[6];
  const float* wo = (const float*)d_in[7];
  const float* bo = (const float*)d_in[8];

  char* ws = (char*)d_ws;
  size_t off = 0;
  auto carve = [&](size_t bytes) {
    void* p = ws + off;
    off = (off + bytes + 255) & ~(size_t)255;
    return p;
  };
  u16* wT      = (u16*)carve((size_t)1152 * 1024 * 2);  // packed [wq|wk|wv]^T
  u16* woT     = (u16*)carve((size_t)1024 * 1024 * 2);
  float* bQKV  = (float*)carve(1152 * 4);
  float* bOut  = (float*)carve(1024 * 4);
  u16* xbf     = (u16*)carve((size_t)4096 * EDIM * 2);
  u16* qkvb    = (u16*)carve((size_t)4096 * QLD * 2);
  u16* vTb     = (u16*)carve((size_t)2 * 64 * SLEN * 2);
  u16* Opart   = (u16*)carve((size_t)NSPLIT * 32 * 8 * 256 * 64 * 2);  // 16.8 MB
  float* lpart = (float*)carve((size_t)NSPLIT * 32 * 8 * 256 * 4);     // 0.5 MB
  u16* aob     = (u16*)carve((size_t)4096 * EDIM * 2);

  // prep: weight transposes + bias + x-convert (one grid)
  prep_w<<<dim3(16, 51), 256, 0, stream>>>(wq, wk, wv, wo, bq, bk, bv, bo, x,
                                           wT, woT, bQKV, bOut, xbf);

  // QKV projection (+ fused V-transpose): [4096][1024] @ [1024][1152]^T
  gemm_bt_bias<<<dim3(9, 64), 256, 0, stream>>>(xbf, wT, bQKV, qkvb, 1024, QLD,
                                                0, vTb);

  // flash attention, split-K over key halves (QBLK=256, KVBLK=128)
  attn_kernel<<<dim3(8, 32, NSPLIT), 256, 0, stream>>>(qkvb, vTb, Opart, lpart);
  reduce_o<<<dim3(16, 32), 256, 0, stream>>>(Opart, lpart, aob);

  // output projection + bo -> d_out (fp32)
  gemm_bt_bias<<<dim3(8, 64), 256, 0, stream>>>(aob, woT, bOut, d_out, 1024,
                                                1024, 1, nullptr);
}